// Round 6
// baseline (274.662 us; speedup 1.0000x reference)
//
#include <hip/hip_runtime.h>

typedef __bf16 bf16;
typedef __bf16 bf16x4 __attribute__((ext_vector_type(4)));
typedef __bf16 bf16x8 __attribute__((ext_vector_type(8)));
typedef float  f32x4  __attribute__((ext_vector_type(4)));

#define MFMA16(a, b, c) __builtin_amdgcn_mfma_f32_16x16x32_bf16((a), (b), (c), 0, 0, 0)
// XOR swizzle for [R][64]-bf16 LDS tiles at 16B (8-elem) granule.
#define SW(row, g) (((row) << 6) + ((((g) ^ ((row) & 7))) << 3))

// 0.125 (1/sqrt(dh)) * log2(e): folded into Q at projection -> attn runs in
// exp2 domain; scores ~N(0,0.3) there, so fixed-max-0 softmax is exact in fp32.
#define QSCALE 0.1803368801111137f

typedef __attribute__((address_space(3))) uint32_t       lds_u32_t;
typedef const __attribute__((address_space(1))) uint32_t glob_u32_t;

__device__ __forceinline__ void ld_lds16(const bf16* g, bf16* l) {
    __builtin_amdgcn_global_load_lds((glob_u32_t*)g, (lds_u32_t*)l, 16, 0, 0);
}

// ---------------------------------------------------------------------------
// prep: X fp32 -> bf16 (blocks 0..4095), weights cast+transpose to [n][k].
// ---------------------------------------------------------------------------
__global__ __launch_bounds__(256) void prep(
    const float* __restrict__ X,
    const float* __restrict__ wq, const float* __restrict__ wk,
    const float* __restrict__ wv, const float* __restrict__ wo,
    bf16* __restrict__ Xb, bf16* __restrict__ wqkvT, bf16* __restrict__ woT)
{
    int bid = blockIdx.x;
    if (bid < 4096) {
        size_t i = ((size_t)bid * 256 + threadIdx.x) * 8;
        const f32x4* s = (const f32x4*)(X + i);
        f32x4 a = s[0], b = s[1];
        bf16x8 o;
        for (int e = 0; e < 4; e++) { o[e] = (bf16)a[e]; o[e + 4] = (bf16)b[e]; }
        *(bf16x8*)(Xb + i) = o;
    } else {
        int idx = (bid - 4096) * 256 + threadIdx.x;
        int which = idx >> 15;
        int r = idx & 32767;
        int kg = r >> 9, n = r & 511;
        const float* w = (which == 0) ? wq : (which == 1) ? wk : (which == 2) ? wv : wo;
        bf16x8 o;
        for (int e = 0; e < 8; e++) o[e] = (bf16)w[(size_t)(kg * 8 + e) * 512 + n];
        bf16* dst = ((which < 3) ? (wqkvT + (size_t)which * 262144) : woT) + (size_t)n * 512 + kg * 8;
        *(bf16x8*)dst = o;
    }
}

// ---------------------------------------------------------------------------
// QKV projection (R4-proven). BK=64, swizzled global_load_lds staging,
// LDS-transposed epilogue, XCD-swizzled grid.
// ---------------------------------------------------------------------------
__global__ __launch_bounds__(256, 4) void gemm_qkv(
    const bf16* __restrict__ Xb, const bf16* __restrict__ WT,
    const float* __restrict__ bq, const float* __restrict__ bk,
    const float* __restrict__ bv,
    bf16* __restrict__ Q, bf16* __restrict__ K, bf16* __restrict__ V)
{
    __shared__ char smem[34816];
    bf16* As = (bf16*)smem;
    bf16* Bs = (bf16*)(smem + 16384);

    const int t = threadIdx.x;
    const int lane = t & 63, wid = t >> 6;
    const int wr = wid >> 1, wc = wid & 1;
    const int lr = lane & 15, quad = lane >> 4;
    const int bid = blockIdx.x;
    const int xcd = bid & 7, j0 = bid >> 3;
    const int m0 = (xcd * 16 + (j0 & 15)) * 128;
    const int x = j0 >> 4;
    const int which = x >> 2;
    const int n0 = (x & 3) * 128;
    const bf16* Wt = WT + (size_t)which * 262144;

    f32x4 zf = {0.f, 0.f, 0.f, 0.f};
    f32x4 acc[4][4];
    for (int i = 0; i < 4; i++)
        for (int jj = 0; jj < 4; jj++) acc[i][jj] = zf;

    const int srow = t >> 3;
    const int sg = (t & 7) ^ (srow & 7);
    const bf16* gA = Xb + (size_t)(m0 + srow) * 512 + sg * 8;
    const bf16* gB = Wt + (size_t)(n0 + srow) * 512 + sg * 8;
    bf16* lA = As + t * 8;
    bf16* lB = Bs + t * 8;

    for (int k0 = 0; k0 < 512; k0 += 64) {
        for (int p = 0; p < 4; p++) {
            ld_lds16(gA + k0 + p * 32 * 512, lA + p * 2048);
            ld_lds16(gB + k0 + p * 32 * 512, lB + p * 2048);
        }
        __syncthreads();
        for (int kk = 0; kk < 2; ++kk) {
            bf16x8 af[4], bf_[4];
            for (int i = 0; i < 4; i++)
                af[i] = *(const bf16x8*)&As[SW(wr * 64 + i * 16 + lr, kk * 4 + quad)];
            for (int jj = 0; jj < 4; jj++)
                bf_[jj] = *(const bf16x8*)&Bs[SW(wc * 64 + jj * 16 + lr, kk * 4 + quad)];
            for (int i = 0; i < 4; i++)
                for (int jj = 0; jj < 4; jj++)
                    acc[i][jj] = MFMA16(af[i], bf_[jj], acc[i][jj]);
        }
        __syncthreads();
    }

    bf16* OUT = (which == 0) ? Q : (which == 1) ? K : V;
    const float* bias = (which == 0) ? bq : (which == 1) ? bk : bv;
    const float qs = (which == 0) ? QSCALE : 1.0f;

    bf16* Ep = (bf16*)smem + wid * 4352;
    for (int jj = 0; jj < 4; jj++) {
        int n = n0 + wc * 64 + jj * 16 + lr;
        float bb = bias[n];
        for (int i = 0; i < 4; i++) {
            int row = i * 16 + quad * 4;
            for (int r = 0; r < 4; r++)
                Ep[(row + r) * 68 + jj * 16 + lr] = (bf16)((acc[i][jj][r] + bb) * qs);
        }
    }
    bf16* wO = OUT + (size_t)(m0 + wr * 64) * 512 + n0 + wc * 64;
    for (int s = 0; s < 8; s++) {
        int row = s * 8 + (lane >> 3), g = lane & 7;
        *(bf16x8*)(wO + (size_t)row * 512 + g * 8) = *(const bf16x8*)&Ep[row * 68 + g * 8];
    }
}

// ---------------------------------------------------------------------------
// Output projection (R4-proven, fp32 out).
// ---------------------------------------------------------------------------
__global__ __launch_bounds__(256, 4) void gemm_out(
    const bf16* __restrict__ A, const bf16* __restrict__ WoT,
    const float* __restrict__ bo, float* __restrict__ OUT)
{
    __shared__ char smem[34816];
    bf16* As = (bf16*)smem;
    bf16* Bs = (bf16*)(smem + 16384);

    const int t = threadIdx.x;
    const int lane = t & 63, wid = t >> 6;
    const int wr = wid >> 1, wc = wid & 1;
    const int lr = lane & 15, quad = lane >> 4;
    const int bid = blockIdx.x;
    const int xcd = bid & 7, j0 = bid >> 3;
    const int m0 = (xcd * 16 + (j0 & 15)) * 128;
    const int n0 = (j0 >> 4) * 128;

    f32x4 zf = {0.f, 0.f, 0.f, 0.f};
    f32x4 acc[4][4];
    for (int i = 0; i < 4; i++)
        for (int jj = 0; jj < 4; jj++) acc[i][jj] = zf;

    const int srow = t >> 3;
    const int sg = (t & 7) ^ (srow & 7);
    const bf16* gA = A + (size_t)(m0 + srow) * 512 + sg * 8;
    const bf16* gB = WoT + (size_t)(n0 + srow) * 512 + sg * 8;
    bf16* lA = As + t * 8;
    bf16* lB = Bs + t * 8;

    for (int k0 = 0; k0 < 512; k0 += 64) {
        for (int p = 0; p < 4; p++) {
            ld_lds16(gA + k0 + p * 32 * 512, lA + p * 2048);
            ld_lds16(gB + k0 + p * 32 * 512, lB + p * 2048);
        }
        __syncthreads();
        for (int kk = 0; kk < 2; ++kk) {
            bf16x8 af[4], bf_[4];
            for (int i = 0; i < 4; i++)
                af[i] = *(const bf16x8*)&As[SW(wr * 64 + i * 16 + lr, kk * 4 + quad)];
            for (int jj = 0; jj < 4; jj++)
                bf_[jj] = *(const bf16x8*)&Bs[SW(wc * 64 + jj * 16 + lr, kk * 4 + quad)];
            for (int i = 0; i < 4; i++)
                for (int jj = 0; jj < 4; jj++)
                    acc[i][jj] = MFMA16(af[i], bf_[jj], acc[i][jj]);
        }
        __syncthreads();
    }

    float bb[4];
    for (int jj = 0; jj < 4; jj++) bb[jj] = bo[n0 + wc * 64 + jj * 16 + lr];

    float* Ef = (float*)smem + wid * 2112;
    for (int h = 0; h < 2; h++) {
        for (int jj = 0; jj < 4; jj++)
            for (int ii = 0; ii < 2; ii++) {
                int i = h * 2 + ii;
                int row = ii * 16 + quad * 4;
                for (int r = 0; r < 4; r++)
                    Ef[(row + r) * 66 + jj * 16 + lr] = acc[i][jj][r] + bb[jj];
            }
        float* wO = OUT + (size_t)(m0 + wr * 64 + h * 32) * 512 + n0 + wc * 64;
        for (int s = 0; s < 8; s++) {
            int row = s * 4 + (lane >> 4), c = (lane & 15) * 4;
            *(f32x4*)(wO + (size_t)row * 512 + c) = *(const f32x4*)&Ef[row * 66 + c];
        }
        __syncthreads();
    }
}

// ---------------------------------------------------------------------------
// V transpose: V[b][key][dh] -> VT[b][dh][key].
// ---------------------------------------------------------------------------
__global__ __launch_bounds__(256) void transpose_v(
    const bf16* __restrict__ V, bf16* __restrict__ VT)
{
    __shared__ bf16 L[64 * 72];
    const int t = threadIdx.x;
    const int b = blockIdx.y, kb = blockIdx.x;
    const bf16* src = V + ((size_t)b * 1024 + (size_t)kb * 64) * 64;
    const int row = t >> 2, c0 = (t & 3) * 16;
    *(bf16x8*)&L[row * 72 + c0]     = *(const bf16x8*)(src + row * 64 + c0);
    *(bf16x8*)&L[row * 72 + c0 + 8] = *(const bf16x8*)(src + row * 64 + c0 + 8);
    __syncthreads();
    bf16x8 o0, o1;
    for (int e = 0; e < 8; e++) {
        o0[e] = L[(c0 + e) * 72 + row];
        o1[e] = L[(c0 + 8 + e) * 72 + row];
    }
    bf16* dst = VT + ((size_t)b * 64 + row) * 1024 + (size_t)kb * 64 + c0;
    *(bf16x8*)dst       = o0;
    *(bf16x8*)(dst + 8) = o1;
}

// ---------------------------------------------------------------------------
// Flash attention, BARRIER-FREE main loop:
// - K A-frags and VT B-frags loaded DIRECTLY from global (16B contiguous,
//   identical across the 4 waves -> L1 serves the intra-block reuse; K/VT
//   are L2-resident under the XCD swizzle).
// - Pt (P round-trip) is wave-private LDS; epilogue scratch reuses the
//   wave's own Pt bytes with an XOR swizzle -> zero __syncthreads total.
// ---------------------------------------------------------------------------
__global__ __launch_bounds__(256, 4) void attn(
    const bf16* __restrict__ Q, const bf16* __restrict__ K,
    const bf16* __restrict__ VT, bf16* __restrict__ O)
{
    __shared__ char smem[16384];
    bf16* Pt = (bf16*)smem;              // [128 q][64 key] swizzled, wave-private rows

    const int t = threadIdx.x, lane = t & 63, wid = t >> 6;
    const int lr = lane & 15, quad = lane >> 4;
    const int bid = blockIdx.x;                     // 1024 blocks
    const int batch = (bid & 7) * 16 + ((bid >> 3) & 15);
    const int q0 = (bid >> 7) * 128;
    const bf16* Qb = Q + (size_t)batch * 65536;
    const bf16* Kb = K + (size_t)batch * 65536;
    const bf16* Vb = VT + (size_t)batch * 65536;

    // Q B-frags in registers (reused by all 16 key-tiles)
    bf16x8 qf[2][2];
    for (int jt = 0; jt < 2; jt++)
        for (int kk = 0; kk < 2; kk++)
            qf[jt][kk] = *(const bf16x8*)(Qb + (size_t)(q0 + wid * 32 + jt * 16 + lr) * 64 + kk * 32 + quad * 8);

    float lsum[2] = {0.f, 0.f};
    f32x4 zf = {0.f, 0.f, 0.f, 0.f};
    f32x4 oacc[2][4];
    for (int a = 0; a < 2; a++)
        for (int b = 0; b < 4; b++) oacc[a][b] = zf;

    // per-lane global frag bases
    const bf16* kbase = Kb + (size_t)lr * 64 + quad * 8;    // + (key0+i*16)*64 + kk*32
    const bf16* vbase = Vb + (size_t)lr * 1024 + quad * 8;  // + nt*16*1024 + key0 + kk*32

    for (int kt = 0; kt < 16; ++kt) {
        const int key0 = kt * 64;

        // K A-frags direct from global (8 x b128)
        bf16x8 af[2][4];
        #pragma unroll
        for (int kk = 0; kk < 2; ++kk)
            #pragma unroll
            for (int i = 0; i < 4; i++)
                af[kk][i] = *(const bf16x8*)(kbase + (size_t)(key0 + i * 16) * 64 + kk * 32);

        // S^T[key][q] = K[key][d] . Q[q][d]
        f32x4 sacc[4][2];
        for (int i = 0; i < 4; i++)
            for (int jt = 0; jt < 2; jt++) sacc[i][jt] = zf;
        #pragma unroll
        for (int kk = 0; kk < 2; ++kk)
            for (int i = 0; i < 4; i++)
                for (int jt = 0; jt < 2; jt++)
                    sacc[i][jt] = MFMA16(af[kk][i], qf[jt][kk], sacc[i][jt]);

        // V B-frags direct from global, issued before softmax to hide latency
        bf16x8 bv_[2][4];
        #pragma unroll
        for (int kk = 0; kk < 2; ++kk)
            #pragma unroll
            for (int nt = 0; nt < 4; nt++)
                bv_[kk][nt] = *(const bf16x8*)(vbase + (size_t)nt * 16384 + key0 + kk * 32);

        // fixed-max softmax: p = exp2(s), P -> wave-private Pt
        for (int jt = 0; jt < 2; jt++) {
            const int qrow = wid * 32 + jt * 16 + lr;
            const int pbase = (qrow << 6) + (quad & 1) * 4;
            float ss = 0.f;
            for (int i = 0; i < 4; i++) {
                bf16x4 pb;
                for (int r = 0; r < 4; r++) {
                    float p = __builtin_amdgcn_exp2f(sacc[i][jt][r]);
                    ss += p;
                    pb[r] = (bf16)p;
                }
                *(bf16x4*)&Pt[pbase + ((((i * 2 + (quad >> 1)) ^ (qrow & 7))) << 3)] = pb;
            }
            lsum[jt] += ss;
        }

        // O += P * V (Pt rows wave-private; compiler orders via lgkmcnt)
        #pragma unroll
        for (int kk = 0; kk < 2; ++kk) {
            bf16x8 ap[2];
            for (int mt = 0; mt < 2; mt++)
                ap[mt] = *(const bf16x8*)&Pt[SW(wid * 32 + mt * 16 + lr, kk * 4 + quad)];
            for (int mt = 0; mt < 2; mt++)
                for (int nt = 0; nt < 4; nt++)
                    oacc[mt][nt] = MFMA16(ap[mt], bv_[kk][nt], oacc[mt][nt]);
        }
    }

    for (int jt = 0; jt < 2; jt++) {
        lsum[jt] += __shfl_xor(lsum[jt], 16, 64);
        lsum[jt] += __shfl_xor(lsum[jt], 32, 64);
    }
    float invl[2] = {1.f / lsum[0], 1.f / lsum[1]};

    // epilogue: O/l -> wave's OWN Pt bytes (XOR-swizzled [32][64]) -> dense rows
    bf16* Ep = Pt + wid * 2048;
    for (int mt = 0; mt < 2; mt++)
        for (int r = 0; r < 4; r++) {
            float im = __shfl(invl[mt], quad * 4 + r, 64);
            int row = mt * 16 + quad * 4 + r;
            for (int nt = 0; nt < 4; nt++) {
                int g = nt * 2 + (lr >> 3);
                Ep[(row << 6) + ((g ^ (row & 7)) << 3) + (lr & 7)] = (bf16)(oacc[mt][nt][r] * im);
            }
        }
    bf16* Ob = O + (size_t)batch * 65536 + (size_t)(q0 + wid * 32) * 64;
    for (int s = 0; s < 4; s++) {
        int row = s * 8 + (lane >> 3), g = lane & 7;
        *(bf16x8*)(Ob + (size_t)row * 64 + g * 8) =
            *(const bf16x8*)&Ep[(row << 6) + ((g ^ (row & 7)) << 3)];
    }
}

// ---------------------------------------------------------------------------
extern "C" void kernel_launch(void* const* d_in, const int* in_sizes, int n_in,
                              void* d_out, int out_size, void* d_ws, size_t ws_size,
                              hipStream_t stream)
{
    const float* x  = (const float*)d_in[0];
    const float* wq = (const float*)d_in[1];
    const float* bq = (const float*)d_in[2];
    const float* wk = (const float*)d_in[3];
    const float* bk = (const float*)d_in[4];
    const float* wv = (const float*)d_in[5];
    const float* bv = (const float*)d_in[6];
    const float* wo = (const float*)d_in[7];
    const float* bo = (const float*)d_in[8];

    char* ws = (char*)d_ws;
    bf16* wqkvT = (bf16*)ws;                                  // 1.5 MB
    bf16* woT   = (bf16*)(ws + 1572864);                      // 0.5 MB
    bf16* Xb    = (bf16*)(ws + 2097152);                      // 16 MB (later: VT)
    bf16* VTb   = Xb;                                         // alias: Xb dead after gemm_qkv
    bf16* Qb    = (bf16*)(ws + 2097152 + 16777216ull);
    bf16* Kb    = (bf16*)(ws + 2097152 + 2 * 16777216ull);
    bf16* Vb    = (bf16*)(ws + 2097152 + 3 * 16777216ull);
    bf16* Ab    = Vb;                                         // alias: Vb dead after transpose_v

    prep<<<4608, 256, 0, stream>>>(x, wq, wk, wv, wo, Xb, wqkvT, woT);
    gemm_qkv<<<1536, 256, 0, stream>>>(Xb, wqkvT, bq, bk, bv, Qb, Kb, Vb);
    transpose_v<<<dim3(16, 128), 256, 0, stream>>>(Vb, VTb);
    attn<<<1024, 256, 0, stream>>>(Qb, Kb, VTb, Ab);
    gemm_out<<<512, 256, 0, stream>>>(Ab, woT, bo, (float*)d_out);
}

// Round 7
// 210.185 us; speedup vs baseline: 1.3068x; 1.3068x over previous
//
#include <hip/hip_runtime.h>

typedef __bf16 bf16;
typedef __bf16 bf16x4 __attribute__((ext_vector_type(4)));
typedef __bf16 bf16x8 __attribute__((ext_vector_type(8)));
typedef float  f32x4  __attribute__((ext_vector_type(4)));

#define MFMA16(a, b, c) __builtin_amdgcn_mfma_f32_16x16x32_bf16((a), (b), (c), 0, 0, 0)
// XOR swizzle for [R][64]-bf16 LDS tiles at 16B (8-elem) granule.
#define SW(row, g) (((row) << 6) + ((((g) ^ ((row) & 7))) << 3))

// 0.125 (1/sqrt(dh)) * log2(e): folded into Q at projection -> attn runs in
// exp2 domain; scores ~N(0,0.3) there, so fixed-max-0 softmax is exact in fp32.
#define QSCALE 0.1803368801111137f

typedef __attribute__((address_space(3))) uint32_t       lds_u32_t;
typedef const __attribute__((address_space(1))) uint32_t glob_u32_t;

__device__ __forceinline__ void ld_lds16(const bf16* g, bf16* l) {
    __builtin_amdgcn_global_load_lds((glob_u32_t*)g, (lds_u32_t*)l, 16, 0, 0);
}

// ---------------------------------------------------------------------------
// prep_w: weights only — cast fp32 -> bf16 and transpose to [n][k].
// (X cast is now fused into gemm_qkv's A-staging.)
// ---------------------------------------------------------------------------
__global__ __launch_bounds__(256) void prep_w(
    const float* __restrict__ wq, const float* __restrict__ wk,
    const float* __restrict__ wv, const float* __restrict__ wo,
    bf16* __restrict__ wqkvT, bf16* __restrict__ woT)
{
    int idx = blockIdx.x * 256 + threadIdx.x;     // 0..131071
    int which = idx >> 15;
    int r = idx & 32767;
    int kg = r >> 9, n = r & 511;
    const float* w = (which == 0) ? wq : (which == 1) ? wk : (which == 2) ? wv : wo;
    bf16x8 o;
    for (int e = 0; e < 8; e++) o[e] = (bf16)w[(size_t)(kg * 8 + e) * 512 + n];
    bf16* dst = ((which < 3) ? (wqkvT + (size_t)which * 262144) : woT) + (size_t)n * 512 + kg * 8;
    *(bf16x8*)dst = o;
}

// ---------------------------------------------------------------------------
// QKV projection, fp32 X input (cast during A-staging), BK=64.
// A: f32x4 loads -> cvt -> swizzled ds_write_b128. B: global_load_lds (bf16).
// Block order per XCD: the 12 n/which tiles INNER (j%12) so each 256KB fp32
// X m-tile is fetched once and stays L2-resident; weights (1.5MB) L2-resident.
// ---------------------------------------------------------------------------
__global__ __launch_bounds__(256, 4) void gemm_qkv(
    const float* __restrict__ X, const bf16* __restrict__ WT,
    const float* __restrict__ bq, const float* __restrict__ bk,
    const float* __restrict__ bv,
    bf16* __restrict__ Q, bf16* __restrict__ K, bf16* __restrict__ V)
{
    __shared__ char smem[34816];
    bf16* As = (bf16*)smem;
    bf16* Bs = (bf16*)(smem + 16384);

    const int t = threadIdx.x;
    const int lane = t & 63, wid = t >> 6;
    const int wr = wid >> 1, wc = wid & 1;
    const int lr = lane & 15, quad = lane >> 4;
    const int bid = blockIdx.x;
    const int xcd = bid & 7, j0 = bid >> 3;       // j0 in 0..191
    const int msub = j0 / 12;                     // 0..15 (outer)
    const int x = j0 - msub * 12;                 // 0..11 (inner)
    const int m0 = (xcd * 16 + msub) * 128;
    const int which = x >> 2;
    const int n0 = (x & 3) * 128;
    const bf16* Wt = WT + (size_t)which * 262144;

    f32x4 zf = {0.f, 0.f, 0.f, 0.f};
    f32x4 acc[4][4];
    for (int i = 0; i < 4; i++)
        for (int jj = 0; jj < 4; jj++) acc[i][jj] = zf;

    // A staging: thread t covers rows (t>>3)+32p, natural granule t&7;
    // reads 32B fp32 (coalesced: 8 lanes x 32B = 256B/row), writes swizzled b128.
    const int arow = t >> 3, ag = t & 7;
    const float* gX = X + (size_t)(m0 + arow) * 512 + ag * 8;
    // B staging: global_load_lds with swizzle-inverted source granule.
    const int sg = ag ^ (arow & 7);
    const bf16* gB = Wt + (size_t)(n0 + arow) * 512 + sg * 8;
    bf16* lB = Bs + t * 8;

    for (int k0 = 0; k0 < 512; k0 += 64) {
        for (int p = 0; p < 4; p++)
            ld_lds16(gB + k0 + p * 32 * 512, lB + p * 2048);
        #pragma unroll
        for (int p = 0; p < 4; p++) {
            const f32x4* s = (const f32x4*)(gX + (size_t)(p * 32) * 512 + k0);
            f32x4 a = s[0], b = s[1];
            bf16x8 o;
            for (int e = 0; e < 4; e++) { o[e] = (bf16)a[e]; o[e + 4] = (bf16)b[e]; }
            *(bf16x8*)&As[SW(arow + p * 32, ag)] = o;
        }
        __syncthreads();
        for (int kk = 0; kk < 2; ++kk) {
            bf16x8 af[4], bf_[4];
            for (int i = 0; i < 4; i++)
                af[i] = *(const bf16x8*)&As[SW(wr * 64 + i * 16 + lr, kk * 4 + quad)];
            for (int jj = 0; jj < 4; jj++)
                bf_[jj] = *(const bf16x8*)&Bs[SW(wc * 64 + jj * 16 + lr, kk * 4 + quad)];
            for (int i = 0; i < 4; i++)
                for (int jj = 0; jj < 4; jj++)
                    acc[i][jj] = MFMA16(af[i], bf_[jj], acc[i][jj]);
        }
        __syncthreads();
    }

    bf16* OUT = (which == 0) ? Q : (which == 1) ? K : V;
    const float* bias = (which == 0) ? bq : (which == 1) ? bk : bv;
    const float qs = (which == 0) ? QSCALE : 1.0f;

    bf16* Ep = (bf16*)smem + wid * 4352;
    for (int jj = 0; jj < 4; jj++) {
        int n = n0 + wc * 64 + jj * 16 + lr;
        float bb = bias[n];
        for (int i = 0; i < 4; i++) {
            int row = i * 16 + quad * 4;
            for (int r = 0; r < 4; r++)
                Ep[(row + r) * 68 + jj * 16 + lr] = (bf16)((acc[i][jj][r] + bb) * qs);
        }
    }
    bf16* wO = OUT + (size_t)(m0 + wr * 64) * 512 + n0 + wc * 64;
    for (int s = 0; s < 8; s++) {
        int row = s * 8 + (lane >> 3), g = lane & 7;
        *(bf16x8*)(wO + (size_t)row * 512 + g * 8) = *(const bf16x8*)&Ep[row * 68 + g * 8];
    }
}

// ---------------------------------------------------------------------------
// Output projection (R4-proven, fp32 out).
// ---------------------------------------------------------------------------
__global__ __launch_bounds__(256, 4) void gemm_out(
    const bf16* __restrict__ A, const bf16* __restrict__ WoT,
    const float* __restrict__ bo, float* __restrict__ OUT)
{
    __shared__ char smem[34816];
    bf16* As = (bf16*)smem;
    bf16* Bs = (bf16*)(smem + 16384);

    const int t = threadIdx.x;
    const int lane = t & 63, wid = t >> 6;
    const int wr = wid >> 1, wc = wid & 1;
    const int lr = lane & 15, quad = lane >> 4;
    const int bid = blockIdx.x;
    const int xcd = bid & 7, j0 = bid >> 3;
    const int m0 = (xcd * 16 + (j0 & 15)) * 128;
    const int n0 = (j0 >> 4) * 128;

    f32x4 zf = {0.f, 0.f, 0.f, 0.f};
    f32x4 acc[4][4];
    for (int i = 0; i < 4; i++)
        for (int jj = 0; jj < 4; jj++) acc[i][jj] = zf;

    const int srow = t >> 3;
    const int sg = (t & 7) ^ (srow & 7);
    const bf16* gA = A + (size_t)(m0 + srow) * 512 + sg * 8;
    const bf16* gB = WoT + (size_t)(n0 + srow) * 512 + sg * 8;
    bf16* lA = As + t * 8;
    bf16* lB = Bs + t * 8;

    for (int k0 = 0; k0 < 512; k0 += 64) {
        for (int p = 0; p < 4; p++) {
            ld_lds16(gA + k0 + p * 32 * 512, lA + p * 2048);
            ld_lds16(gB + k0 + p * 32 * 512, lB + p * 2048);
        }
        __syncthreads();
        for (int kk = 0; kk < 2; ++kk) {
            bf16x8 af[4], bf_[4];
            for (int i = 0; i < 4; i++)
                af[i] = *(const bf16x8*)&As[SW(wr * 64 + i * 16 + lr, kk * 4 + quad)];
            for (int jj = 0; jj < 4; jj++)
                bf_[jj] = *(const bf16x8*)&Bs[SW(wc * 64 + jj * 16 + lr, kk * 4 + quad)];
            for (int i = 0; i < 4; i++)
                for (int jj = 0; jj < 4; jj++)
                    acc[i][jj] = MFMA16(af[i], bf_[jj], acc[i][jj]);
        }
        __syncthreads();
    }

    float bb[4];
    for (int jj = 0; jj < 4; jj++) bb[jj] = bo[n0 + wc * 64 + jj * 16 + lr];

    float* Ef = (float*)smem + wid * 2112;
    for (int h = 0; h < 2; h++) {
        for (int jj = 0; jj < 4; jj++)
            for (int ii = 0; ii < 2; ii++) {
                int i = h * 2 + ii;
                int row = ii * 16 + quad * 4;
                for (int r = 0; r < 4; r++)
                    Ef[(row + r) * 66 + jj * 16 + lr] = acc[i][jj][r] + bb[jj];
            }
        float* wO = OUT + (size_t)(m0 + wr * 64 + h * 32) * 512 + n0 + wc * 64;
        for (int s = 0; s < 8; s++) {
            int row = s * 4 + (lane >> 4), c = (lane & 15) * 4;
            *(f32x4*)(wO + (size_t)row * 512 + c) = *(const f32x4*)&Ef[row * 66 + c];
        }
        __syncthreads();
    }
}

// ---------------------------------------------------------------------------
// V transpose: V[b][key][dh] -> VT[b][dh][key].
// ---------------------------------------------------------------------------
__global__ __launch_bounds__(256) void transpose_v(
    const bf16* __restrict__ V, bf16* __restrict__ VT)
{
    __shared__ bf16 L[64 * 72];
    const int t = threadIdx.x;
    const int b = blockIdx.y, kb = blockIdx.x;
    const bf16* src = V + ((size_t)b * 1024 + (size_t)kb * 64) * 64;
    const int row = t >> 2, c0 = (t & 3) * 16;
    *(bf16x8*)&L[row * 72 + c0]     = *(const bf16x8*)(src + row * 64 + c0);
    *(bf16x8*)&L[row * 72 + c0 + 8] = *(const bf16x8*)(src + row * 64 + c0 + 8);
    __syncthreads();
    bf16x8 o0, o1;
    for (int e = 0; e < 8; e++) {
        o0[e] = L[(c0 + e) * 72 + row];
        o1[e] = L[(c0 + 8 + e) * 72 + row];
    }
    bf16* dst = VT + ((size_t)b * 64 + row) * 1024 + (size_t)kb * 64 + c0;
    *(bf16x8*)dst       = o0;
    *(bf16x8*)(dst + 8) = o1;
}

// ---------------------------------------------------------------------------
// Flash attention (R4-proven). Q B-frags in registers, 32KB LDS -> 4 blocks/CU
// full co-residency; fixed-max exp2 softmax; register-prefetch K/V;
// LDS-transposed O epilogue. XCD-swizzled grid.
// ---------------------------------------------------------------------------
__global__ __launch_bounds__(256, 4) void attn(
    const bf16* __restrict__ Q, const bf16* __restrict__ K,
    const bf16* __restrict__ VT, bf16* __restrict__ O)
{
    __shared__ char smem[32768];
    bf16* Kt = (bf16*)smem;              // [64][64] swizzled
    bf16* Vt = (bf16*)(smem + 8192);     // [64][64] swizzled ([dh][key])
    bf16* Pt = (bf16*)(smem + 16384);    // [128][64] swizzled

    const int t = threadIdx.x, lane = t & 63, wid = t >> 6;
    const int lr = lane & 15, quad = lane >> 4;
    const int bid = blockIdx.x;                     // 1024 blocks
    const int batch = (bid & 7) * 16 + ((bid >> 3) & 15);
    const int q0 = (bid >> 7) * 128;
    const bf16* Qb = Q + (size_t)batch * 65536;
    const bf16* Kb = K + (size_t)batch * 65536;
    const bf16* Vb = VT + (size_t)batch * 65536;

    bf16x8 qf[2][2];
    for (int jt = 0; jt < 2; jt++)
        for (int kk = 0; kk < 2; kk++)
            qf[jt][kk] = *(const bf16x8*)(Qb + (size_t)(q0 + wid * 32 + jt * 16 + lr) * 64 + kk * 32 + quad * 8);

    float lsum[2] = {0.f, 0.f};
    f32x4 zf = {0.f, 0.f, 0.f, 0.f};
    f32x4 oacc[2][4];
    for (int a = 0; a < 2; a++)
        for (int b = 0; b < 4; b++) oacc[a][b] = zf;

    const int vrow = t >> 2, vg = (t & 3) * 2;
    const bf16* gK = Kb + (size_t)vrow * 64 + (t & 3) * 16;    // +kt*4096
    const bf16* gV = Vb + (size_t)vrow * 1024 + (t & 3) * 16;  // +kt*64

    bf16x8 kr0 = ((const bf16x8*)gK)[0], kr1 = ((const bf16x8*)gK)[1];
    bf16x8 vr0 = ((const bf16x8*)gV)[0], vr1 = ((const bf16x8*)gV)[1];

    for (int kt = 0; kt < 16; ++kt) {
        __syncthreads();
        *(bf16x8*)&Kt[SW(vrow, vg)]     = kr0;
        *(bf16x8*)&Kt[SW(vrow, vg + 1)] = kr1;
        *(bf16x8*)&Vt[SW(vrow, vg)]     = vr0;
        *(bf16x8*)&Vt[SW(vrow, vg + 1)] = vr1;
        __syncthreads();

        if (kt < 15) {
            const bf16x8* nK = (const bf16x8*)(gK + (kt + 1) * 4096);
            const bf16x8* nV = (const bf16x8*)(gV + (kt + 1) * 64);
            kr0 = nK[0]; kr1 = nK[1];
            vr0 = nV[0]; vr1 = nV[1];
        }

        f32x4 sacc[4][2];
        for (int i = 0; i < 4; i++)
            for (int jt = 0; jt < 2; jt++) sacc[i][jt] = zf;
        for (int kk = 0; kk < 2; ++kk) {
            bf16x8 af[4];
            for (int i = 0; i < 4; i++)
                af[i] = *(const bf16x8*)&Kt[SW(i * 16 + lr, kk * 4 + quad)];
            for (int i = 0; i < 4; i++)
                for (int jt = 0; jt < 2; jt++)
                    sacc[i][jt] = MFMA16(af[i], qf[jt][kk], sacc[i][jt]);
        }

        for (int jt = 0; jt < 2; jt++) {
            const int qrow = wid * 32 + jt * 16 + lr;
            const int pbase = (qrow << 6) + (quad & 1) * 4;
            float ss = 0.f;
            for (int i = 0; i < 4; i++) {
                bf16x4 pb;
                for (int r = 0; r < 4; r++) {
                    float p = __builtin_amdgcn_exp2f(sacc[i][jt][r]);
                    ss += p;
                    pb[r] = (bf16)p;
                }
                *(bf16x4*)&Pt[pbase + ((((i * 2 + (quad >> 1)) ^ (qrow & 7))) << 3)] = pb;
            }
            lsum[jt] += ss;
        }

        for (int kk = 0; kk < 2; ++kk) {
            bf16x8 ap[2], bv_[4];
            for (int mt = 0; mt < 2; mt++)
                ap[mt] = *(const bf16x8*)&Pt[SW(wid * 32 + mt * 16 + lr, kk * 4 + quad)];
            for (int nt = 0; nt < 4; nt++)
                bv_[nt] = *(const bf16x8*)&Vt[SW(nt * 16 + lr, kk * 4 + quad)];
            for (int mt = 0; mt < 2; mt++)
                for (int nt = 0; nt < 4; nt++)
                    oacc[mt][nt] = MFMA16(ap[mt], bv_[nt], oacc[mt][nt]);
        }
    }

    for (int jt = 0; jt < 2; jt++) {
        lsum[jt] += __shfl_xor(lsum[jt], 16, 64);
        lsum[jt] += __shfl_xor(lsum[jt], 32, 64);
    }
    float invl[2] = {1.f / lsum[0], 1.f / lsum[1]};

    __syncthreads();
    bf16* Ep = (bf16*)smem + wid * 2176;
    for (int mt = 0; mt < 2; mt++)
        for (int r = 0; r < 4; r++) {
            float im = __shfl(invl[mt], quad * 4 + r, 64);
            int row = mt * 16 + quad * 4 + r;
            for (int nt = 0; nt < 4; nt++)
                Ep[row * 68 + nt * 16 + lr] = (bf16)(oacc[mt][nt][r] * im);
        }
    bf16* Ob = O + (size_t)batch * 65536 + (size_t)(q0 + wid * 32) * 64;
    for (int s = 0; s < 4; s++) {
        int row = s * 8 + (lane >> 3), g = lane & 7;
        *(bf16x8*)(Ob + (size_t)row * 64 + g * 8) = *(const bf16x8*)&Ep[row * 68 + g * 8];
    }
}

// ---------------------------------------------------------------------------
extern "C" void kernel_launch(void* const* d_in, const int* in_sizes, int n_in,
                              void* d_out, int out_size, void* d_ws, size_t ws_size,
                              hipStream_t stream)
{
    const float* x  = (const float*)d_in[0];
    const float* wq = (const float*)d_in[1];
    const float* bq = (const float*)d_in[2];
    const float* wk = (const float*)d_in[3];
    const float* bk = (const float*)d_in[4];
    const float* wv = (const float*)d_in[5];
    const float* bv = (const float*)d_in[6];
    const float* wo = (const float*)d_in[7];
    const float* bo = (const float*)d_in[8];

    char* ws = (char*)d_ws;
    bf16* wqkvT = (bf16*)ws;                                  // 1.5 MB
    bf16* woT   = (bf16*)(ws + 1572864);                      // 0.5 MB
    bf16* Qb    = (bf16*)(ws + 2097152);                      // 16 MB each
    bf16* Kb    = (bf16*)(ws + 2097152 + 16777216ull);
    bf16* Vb    = (bf16*)(ws + 2097152 + 2 * 16777216ull);
    bf16* VTb   = (bf16*)(ws + 2097152 + 3 * 16777216ull);
    bf16* Ab    = Vb;                                         // alias: Vb dead after transpose_v

    prep_w<<<512, 256, 0, stream>>>(wq, wk, wv, wo, wqkvT, woT);
    gemm_qkv<<<1536, 256, 0, stream>>>(x, wqkvT, bq, bk, bv, Qb, Kb, Vb);
    transpose_v<<<dim3(16, 128), 256, 0, stream>>>(Vb, VTb);
    attn<<<1024, 256, 0, stream>>>(Qb, Kb, VTb, Ab);
    gemm_out<<<512, 256, 0, stream>>>(Ab, woT, bo, (float*)d_out);
}